// Round 5
// baseline (350.354 us; speedup 1.0000x reference)
//
#include <hip/hip_runtime.h>

constexpr int NB = 16;
constexpr int NCI = 64;
constexpr int NCO = 64;
constexpr int NH = 256;
constexpr int NW = 256;
constexpr int NM1 = 20;
constexpr int NM2 = 20;
constexpr int NMODES = 400;

// workspace layout (float offsets)
constexpr long OFF_TWS  = 0;                                  // fwd twiddle [256][48]
constexpr long OFF_TINV = 12288;                              // Tc[20][16][12] | Ts[20][16][12]
constexpr long OFF_XL   = OFF_TINV + 7680;                    // [NB][NCI][400][2]
constexpr long OFF_OL   = OFF_XL + (long)NB*NCI*NMODES*2;     // [NB][NCO][400][2]

constexpr float TWO_PI = 6.28318530717958647692f;
constexpr float INV_N2 = 1.0f / 65536.0f;

// ---------------- table init ----------------------------------------------------
__global__ void init_tabs(float* __restrict__ ws) {
    int e = blockIdx.x * 256 + threadIdx.x;
    if (e < 12288) {
        int w = e / 48, s = e % 48;
        int cg = s / 12, q = s % 12;
        float v = 0.f;
        if (q < 10) {
            int n = 10 * cg + q, ky = n >> 1, p = n & 1;
            float ang = TWO_PI * (float)((ky * w) & 255) * (1.0f / 256.0f);
            float sn, cn; sincosf(ang, &sn, &cn);
            v = p ? -sn : cn;
        }
        ws[OFF_TWS + e] = v;
    } else if (e < 19968) {
        int f = e - 12288;
        int tb = f / 3840, rr = f % 3840;
        int ky = rr / 192, g = (rr % 192) / 12, q = rr % 12;
        float v = 0.f;
        if (q < 8) {
            int w = 8 * g + 1 + q;
            float ang = TWO_PI * (float)((ky * w) & 255) * (1.0f / 256.0f);
            float sn, cn; sincosf(ang, &sn, &cn);
            float cky = (ky == 0) ? 1.0f : 2.0f;
            v = (tb == 0 ? cn : sn) * cky * INV_N2;
        }
        ws[OFF_TINV + f] = v;
    }
}

// ---------------- forward: x -> X_low (fused W-DFT then H-DFT) ------------------
// one block per (b*64+i); 256 threads; 3 blocks/CU
__launch_bounds__(256, 3)
__global__ void fwd_kernel(const float* __restrict__ x, float* __restrict__ ws) {
    __shared__ float sm[10752];        // 43008 B -> 3 blocks/CU
    float* sX = sm;                    // [256][32] swizzled x chunk (8192), phase 1
    float* sT = sm + 8192;             // [32][48] twiddle chunk (1536),   phase 1
    float* sA = sm;                    // [256][40] A[h][n] (10240),       phase 2
    float2* csp = (float2*)(sm + 10240); // [256] cos/sin,                 phase 2
    const int t = threadIdx.x;
    const int r = blockIdx.x;                 // b*64+i
    const float* xr = x + (long)r * (NH * NW);
    const float* tws = ws + OFF_TWS;

    const int rg = t >> 2;    // [0,64): h = rg + 64*rr
    const int cg = t & 3;     // [0,4):  n = 10*cg + q
    const int sw = rg & 7;    // x column swizzle key (h&7 == rg&7 for all rr)

    float acc[4][10];
#pragma unroll
    for (int a0 = 0; a0 < 4; a0++)
#pragma unroll
        for (int a1 = 0; a1 < 10; a1++) acc[a0][a1] = 0.f;

    // staging registers
    float4 g[8];
    float4 tg0, tg1;
    const int sh_ = t >> 3, sq_ = t & 7;      // rows h = sh_ + 32*j, cols 4*sq_

    // prologue: issue loads for chunk 0
#pragma unroll
    for (int j = 0; j < 8; ++j)
        g[j] = *(const float4*)(xr + (long)(sh_ + 32*j) * NW + 4*sq_);
    tg0 = *(const float4*)(tws + 4*t);
    if (t < 128) tg1 = *(const float4*)(tws + 1024 + 4*t);

    for (int kc = 0; kc < 8; ++kc) {
        __syncthreads();   // previous compute done reading sX/sT
        // write staged regs -> LDS (swizzled: col group sq_ -> sq_ ^ (h&7))
#pragma unroll
        for (int j = 0; j < 8; ++j) {
            int h = sh_ + 32*j;
            *(float4*)(sX + h*32 + 4*(sq_ ^ (h & 7))) = g[j];
        }
        *(float4*)(sT + 4*t) = tg0;
        if (t < 128) *(float4*)(sT + 1024 + 4*t) = tg1;
        __syncthreads();
        // issue loads for chunk kc+1
        if (kc < 7) {
            const float* xc = xr + (kc + 1) * 32;
#pragma unroll
            for (int j = 0; j < 8; ++j)
                g[j] = *(const float4*)(xc + (long)(sh_ + 32*j) * NW + 4*sq_);
            const float* tc = tws + (long)(kc + 1) * 1536;
            tg0 = *(const float4*)(tc + 4*t);
            if (t < 128) tg1 = *(const float4*)(tc + 1024 + 4*t);
        }
        // compute chunk kc: 8 w-quads
#pragma unroll 2
        for (int wq = 0; wq < 8; ++wq) {
            float4 xq[4];
            const int xcol = 4 * (wq ^ sw);
#pragma unroll
            for (int rr = 0; rr < 4; ++rr)
                xq[rr] = *(const float4*)(sX + (rg + 64*rr)*32 + xcol);
#pragma unroll
            for (int ww = 0; ww < 4; ++ww) {
                const float* tp = sT + (4*wq + ww)*48 + 12*cg;
                float4 t0 = *(const float4*)(tp);
                float4 t1 = *(const float4*)(tp + 4);
                float4 t2 = *(const float4*)(tp + 8);
                float tv[10] = {t0.x,t0.y,t0.z,t0.w, t1.x,t1.y,t1.z,t1.w, t2.x,t2.y};
                float xa[4] = {xq[0][ww], xq[1][ww], xq[2][ww], xq[3][ww]};
#pragma unroll
                for (int rr = 0; rr < 4; ++rr)
#pragma unroll
                    for (int q = 0; q < 10; ++q)
                        acc[rr][q] += xa[rr] * tv[q];
            }
        }
    }
    __syncthreads();   // all compute done before sA overwrites sX/sT

    // write A[h][n] to LDS; regenerate cos/sin table
#pragma unroll
    for (int rr = 0; rr < 4; ++rr)
#pragma unroll
        for (int q = 0; q < 10; ++q)
            sA[(rg + 64*rr)*40 + 10*cg + q] = acc[rr][q];
    {
        float ang = TWO_PI * (float)t * (1.0f/256.0f);
        float s, c; sincosf(ang, &s, &c);
        csp[t] = make_float2(c, s);
    }
    __syncthreads();

    // phase 2: X_low[kx,ky] = sum_h A[h][.] * e^{-2pi i kx h/256}
    if (t < 200) {
        const int p  = t >> 1;         // 0..99
        const int sh = t & 1;          // h-half; partner = adjacent lane
        const int kxg = p / 10, kyg = p % 10;
        const int kx0 = 2 * kxg;
        float a2[8];
#pragma unroll
        for (int q = 0; q < 8; q++) a2[q] = 0.f;
        for (int it = 0; it < 128; ++it) {
            int h = 128 * sh + it;
            float4 a = *(const float4*)(sA + h*40 + 4*kyg); // re0,im0,re1,im1
            int i0 = (kx0 * h) & 255;
            int i1 = (i0 + h) & 255;
            float2 cs0 = csp[i0];
            float2 cs1 = csp[i1];
            a2[0] += a.x*cs0.x + a.y*cs0.y;  a2[1] += a.y*cs0.x - a.x*cs0.y;
            a2[2] += a.z*cs0.x + a.w*cs0.y;  a2[3] += a.w*cs0.x - a.z*cs0.y;
            a2[4] += a.x*cs1.x + a.y*cs1.y;  a2[5] += a.y*cs1.x - a.x*cs1.y;
            a2[6] += a.z*cs1.x + a.w*cs1.y;  a2[7] += a.w*cs1.x - a.z*cs1.y;
        }
#pragma unroll
        for (int q = 0; q < 8; q++) a2[q] += __shfl_xor(a2[q], 1);
        if (sh == 0) {
            float* xl = ws + OFF_XL + (long)r * (NMODES * 2);
            *(float4*)(xl + 2*(kx0*20 + 2*kyg))       = make_float4(a2[0],a2[1],a2[2],a2[3]);
            *(float4*)(xl + 2*((kx0+1)*20 + 2*kyg))   = make_float4(a2[4],a2[5],a2[6],a2[7]);
        }
    }
}

// ---------------- channel mix: OL[b,o,m] = sum_i X[b,i,m]*W[i,o,m] --------------
__launch_bounds__(256, 4)
__global__ void mix_kernel(const float* __restrict__ wre, const float* __restrict__ wim,
                           float* __restrict__ ws) {
    __shared__ float sw[200];
    __shared__ float sx[800];
    const int t = threadIdx.x;
    const int blk = blockIdx.x;
    const int o  = blk >> 4;
    const int mq = (blk >> 2) & 3;
    const int bq = blk & 3;
    const int m0 = mq * 100;
    const float* XL = ws + OFF_XL;
    float acc[2][2];
    acc[0][0] = acc[0][1] = acc[1][0] = acc[1][1] = 0.f;
    for (int i = 0; i < NCI; ++i) {
        __syncthreads();
        if (t < 100)      sw[t] = wre[(long)(i * NCO + o) * NMODES + m0 + t];
        else if (t < 200) sw[t] = wim[(long)(i * NCO + o) * NMODES + m0 + (t - 100)];
#pragma unroll
        for (int j = 0; j < 4; ++j) {
            int u = t + 256 * j;
            if (u < 800) {
                int bl = u / 200, q = u % 200;
                int b = 4 * bq + bl;
                sx[u] = XL[((long)(b * NCI + i) * NMODES + m0) * 2 + q];
            }
        }
        __syncthreads();
#pragma unroll
        for (int j = 0; j < 2; ++j) {
            int v = t + 256 * j;
            if (v < 400) {
                int bl = v / 100, ml = v % 100;
                float xr = sx[bl*200 + 2*ml], xi = sx[bl*200 + 2*ml + 1];
                float wr = sw[ml], wi = sw[100 + ml];
                acc[j][0] += xr * wr - xi * wi;
                acc[j][1] += xr * wi + xi * wr;
            }
        }
    }
    float* OL = ws + OFF_OL;
#pragma unroll
    for (int j = 0; j < 2; ++j) {
        int v = t + 256 * j;
        if (v < 400) {
            int bl = v / 100, ml = v % 100;
            int b = 4 * bq + bl;
            long a = ((long)(b * NCO + o) * NMODES + m0 + ml) * 2;
            OL[a]     = acc[j][0];
            OL[a + 1] = acc[j][1];
        }
    }
}

// ---------------- inverse: OL -> out (fused H-iDFT then symmetric W-iDFT) -------
// grid 4096: (bo, hq); 256 threads; 3 blocks/CU
__launch_bounds__(256, 3)
__global__ void inv_kernel(const float* __restrict__ ws, float* __restrict__ out) {
    __shared__ float sm2[11712];
    float* sOL = sm2;            // 800
    float* cs  = sm2 + 800;      // 512
    float* sYr = sm2 + 1312;     // [20][68]
    float* sYi = sm2 + 2672;     // [20][68]
    float* sTc = sm2 + 4032;     // [20][16][12]
    float* sTs = sm2 + 7872;     // [20][16][12]
    const int t = threadIdx.x;
    const int blk = blockIdx.x;
    const int bo = blk >> 2;     // b*64+o
    const int hq = blk & 3;

    { float ang = TWO_PI * (float)t * (1.0f/256.0f); float s,c; sincosf(ang,&s,&c);
      cs[2*t] = c; cs[2*t+1] = s; }
    {
        const float* OL = ws + OFF_OL + (long)bo * (NMODES * 2);
#pragma unroll
        for (int j = 0; j < 4; ++j) {
            int u = t + 256 * j;
            if (u < 800) sOL[u] = OL[u];
        }
        const float* TI = ws + OFF_TINV;
#pragma unroll
        for (int j = 0; j < 8; ++j) {
            int u = t + 256 * j;
            if (u < 1920) *(float4*)(sTc + 4*u) = *(const float4*)(TI + 4*u);
        }
    }
    __syncthreads();

    // phase 1: Yc[ky][h] = sum_kx OL[kx][ky] e^{+2pi i kx h/256}
    {
        int hloc = t >> 2, kyq = t & 3;
        int h = hq * 64 + hloc;
        float a[5][2];
#pragma unroll
        for (int kk = 0; kk < 5; kk++) { a[kk][0] = 0.f; a[kk][1] = 0.f; }
        for (int kx = 0; kx < NM1; ++kx) {
            int idx = (kx * h) & 255;
            float c = cs[2*idx], s = cs[2*idx+1];
#pragma unroll
            for (int kk = 0; kk < 5; ++kk) {
                int ky = kyq * 5 + kk;
                float pr = sOL[2*(kx*NM2 + ky)], pi = sOL[2*(kx*NM2 + ky) + 1];
                a[kk][0] += pr * c - pi * s;
                a[kk][1] += pr * s + pi * c;
            }
        }
#pragma unroll
        for (int kk = 0; kk < 5; ++kk) {
            int ky = kyq * 5 + kk;
            sYr[ky*68 + hloc] = a[kk][0];
            sYi[ky*68 + hloc] = a[kk][1];
        }
    }
    __syncthreads();

    // phase 2: U = sum_ky Yr*Tc, V = sum_ky Yi*Ts; out[w]=U-V, out[256-w]=U+V
    {
        const int lg = t & 15;
        const int hg = t >> 4;
        float U[4][8], V[4][8];
#pragma unroll
        for (int rr = 0; rr < 4; rr++)
#pragma unroll
            for (int c = 0; c < 8; c++) { U[rr][c] = 0.f; V[rr][c] = 0.f; }
        for (int ky = 0; ky < 20; ++ky) {
            float4 yr = *(const float4*)(sYr + ky*68 + 4*hg);
            float4 yi = *(const float4*)(sYi + ky*68 + 4*hg);
            const float* tcp = sTc + ky*192 + lg*12;
            const float* tsp = sTs + ky*192 + lg*12;
            float4 c0 = *(const float4*)(tcp), c1 = *(const float4*)(tcp + 4);
            float4 s0 = *(const float4*)(tsp), s1 = *(const float4*)(tsp + 4);
            float ya[4] = {yr.x, yr.y, yr.z, yr.w};
            float yb[4] = {yi.x, yi.y, yi.z, yi.w};
            float tc[8] = {c0.x,c0.y,c0.z,c0.w, c1.x,c1.y,c1.z,c1.w};
            float ts[8] = {s0.x,s0.y,s0.z,s0.w, s1.x,s1.y,s1.z,s1.w};
#pragma unroll
            for (int rr = 0; rr < 4; ++rr)
#pragma unroll
                for (int c = 0; c < 8; ++c) {
                    U[rr][c] += ya[rr] * tc[c];
                    V[rr][c] += yb[rr] * ts[c];
                }
        }
        float* orow0 = out + (long)bo * (NH*NW) + (long)(hq*64 + 4*hg) * NW;
#pragma unroll
        for (int rr = 0; rr < 4; ++rr) {
            float* orow = orow0 + (long)rr * NW;
            float L[8], F[8];
#pragma unroll
            for (int c = 0; c < 8; ++c) { L[c] = U[rr][c] - V[rr][c]; F[c] = U[rr][c] + V[rr][c]; }
            int wl = 8*lg + 1;
            orow[wl] = L[0];
            *(float2*)(orow + wl + 1) = make_float2(L[1], L[2]);
            *(float4*)(orow + wl + 3) = make_float4(L[3], L[4], L[5], L[6]);
            orow[wl + 7] = L[7];
            *(float4*)(orow + 252 - 8*lg) = make_float4(F[3], F[2], F[1], F[0]);
            *(float4*)(orow + 248 - 8*lg) = make_float4(F[7], F[6], F[5], F[4]);
        }
    }
    if (t < 64) {
        float sum = 0.f;
        for (int ky = 0; ky < 20; ++ky)
            sum += sYr[ky*68 + t] * ((ky == 0) ? 1.0f : 2.0f);
        out[(long)bo * (NH*NW) + (long)(hq*64 + t) * NW] = sum * INV_N2;
    }
}

extern "C" void kernel_launch(void* const* d_in, const int* in_sizes, int n_in,
                              void* d_out, int out_size, void* d_ws, size_t ws_size,
                              hipStream_t stream) {
    const float* x   = (const float*)d_in[0];
    const float* wre = (const float*)d_in[1];
    const float* wim = (const float*)d_in[2];
    float* out = (float*)d_out;
    float* ws  = (float*)d_ws;

    init_tabs<<<dim3(78), dim3(256), 0, stream>>>(ws);
    fwd_kernel<<<dim3(NB * NCI), dim3(256), 0, stream>>>(x, ws);
    mix_kernel<<<dim3(1024), dim3(256), 0, stream>>>(wre, wim, ws);
    inv_kernel<<<dim3(NB * NCO * 4), dim3(256), 0, stream>>>(ws, out);
}

// Round 6
// 306.220 us; speedup vs baseline: 1.1441x; 1.1441x over previous
//
#include <hip/hip_runtime.h>

constexpr int NB = 16;
constexpr int NCI = 64;
constexpr int NCO = 64;
constexpr int NH = 256;
constexpr int NW = 256;
constexpr int NM1 = 20;
constexpr int NM2 = 20;
constexpr int NMODES = 400;

// workspace layout (float offsets)
constexpr long OFF_TWS  = 0;                                  // fwd twiddle [256][48]
constexpr long OFF_TINV = 12288;                              // Tc[20][16][12] | Ts[20][16][12]
constexpr long OFF_XL   = OFF_TINV + 7680;                    // [NB][NCI][400][2]
constexpr long OFF_OL   = OFF_XL + (long)NB*NCI*NMODES*2;     // [NB][NCO][400][2]

constexpr float TWO_PI = 6.28318530717958647692f;
constexpr float INV_N2 = 1.0f / 65536.0f;

// async global->LDS, 16 B per lane; LDS dest = wave-uniform base + lane*16
__device__ __forceinline__ void gload16(const float* g, float* l) {
    __builtin_amdgcn_global_load_lds(
        (const __attribute__((address_space(1))) unsigned int*)(g),
        (__attribute__((address_space(3))) unsigned int*)(l), 16, 0, 0);
}

// ---------------- table init ----------------------------------------------------
__global__ void init_tabs(float* __restrict__ ws) {
    int e = blockIdx.x * 256 + threadIdx.x;
    if (e < 12288) {
        int w = e / 48, s = e % 48;
        int cg = s / 12, q = s % 12;
        float v = 0.f;
        if (q < 10) {
            int n = 10 * cg + q, ky = n >> 1, p = n & 1;
            float ang = TWO_PI * (float)((ky * w) & 255) * (1.0f / 256.0f);
            float sn, cn; sincosf(ang, &sn, &cn);
            v = p ? -sn : cn;
        }
        ws[OFF_TWS + e] = v;
    } else if (e < 19968) {
        int f = e - 12288;
        int tb = f / 3840, rr = f % 3840;
        int ky = rr / 192, g = (rr % 192) / 12, q = rr % 12;
        float v = 0.f;
        if (q < 8) {
            int w = 8 * g + 1 + q;
            float ang = TWO_PI * (float)((ky * w) & 255) * (1.0f / 256.0f);
            float sn, cn; sincosf(ang, &sn, &cn);
            float cky = (ky == 0) ? 1.0f : 2.0f;
            v = (tb == 0 ? cn : sn) * cky * INV_N2;
        }
        ws[OFF_TINV + f] = v;
    }
}

// ---------------- forward: x -> X_low (fused W-DFT then H-DFT) ------------------
// one block per (b*64+i); 256 threads; 3 blocks/CU
__launch_bounds__(256, 3)
__global__ void fwd_kernel(const float* __restrict__ x, float* __restrict__ ws) {
    __shared__ float sm[10752];        // 43008 B -> 3 blocks/CU
    float* sX = sm;                    // [256][32] swizzled x chunk (8192), phase 1
    float* sT = sm + 8192;             // [32][48] twiddle chunk (1536),   phase 1
    float* sA = sm;                    // [256][40] A[h][n] (10240),       phase 2
    float2* csp = (float2*)(sm + 10240); // [256] cos/sin,                 phase 2
    const int t = threadIdx.x;
    const int r = blockIdx.x;                 // b*64+i
    const float* xr = x + (long)r * (NH * NW);
    const float* tws = ws + OFF_TWS;

    const int rg = t >> 2;    // [0,64): h = rg + 64*rr
    const int cg = t & 3;     // [0,4):  n = 10*cg + q
    const int sw = rg & 7;    // x column swizzle key (h&7 == rg&7 for all rr)

    const int wid  = t >> 6, lane = t & 63;
    const int lrow = lane >> 3;                 // row within wave's 8-row stripe
    const int lcsw = 4 * ((lane & 7) ^ lrow);   // pre-swizzled source col (floats)

    float acc[4][10];
#pragma unroll
    for (int a0 = 0; a0 < 4; a0++)
#pragma unroll
        for (int a1 = 0; a1 < 10; a1++) acc[a0][a1] = 0.f;

    for (int kc = 0; kc < 8; ++kc) {
        __syncthreads();   // previous compute done reading sX/sT
        // async-stage x chunk (swizzled source, linear LDS dest)
        {
            const float* xc = xr + kc * 32;
#pragma unroll
            for (int j = 0; j < 8; ++j) {
                const int rowbase = j * 32 + wid * 8;     // rowbase&7 == 0
                gload16(xc + (long)(rowbase + lrow) * NW + lcsw, sX + rowbase * 32);
            }
            const float* tcc = tws + (long)kc * 1536;
            gload16(tcc + wid * 256 + 4 * lane, sT + wid * 256);
            if (wid < 2)
                gload16(tcc + (wid + 4) * 256 + 4 * lane, sT + (wid + 4) * 256);
        }
        __syncthreads();   // drains vmcnt -> staged data visible to all
        // compute chunk kc: 8 w-quads
#pragma unroll 2
        for (int wq = 0; wq < 8; ++wq) {
            float4 xq[4];
            const int xcol = 4 * (wq ^ sw);
#pragma unroll
            for (int rr = 0; rr < 4; ++rr)
                xq[rr] = *(const float4*)(sX + (rg + 64*rr)*32 + xcol);
#pragma unroll
            for (int ww = 0; ww < 4; ++ww) {
                const float* tp = sT + (4*wq + ww)*48 + 12*cg;
                float4 t0 = *(const float4*)(tp);
                float4 t1 = *(const float4*)(tp + 4);
                float4 t2 = *(const float4*)(tp + 8);
                float tv[10] = {t0.x,t0.y,t0.z,t0.w, t1.x,t1.y,t1.z,t1.w, t2.x,t2.y};
                float xa[4] = {xq[0][ww], xq[1][ww], xq[2][ww], xq[3][ww]};
#pragma unroll
                for (int rr = 0; rr < 4; ++rr)
#pragma unroll
                    for (int q = 0; q < 10; ++q)
                        acc[rr][q] += xa[rr] * tv[q];
            }
        }
    }
    __syncthreads();   // all compute done before sA overwrites sX/sT

    // write A[h][n] to LDS; regenerate cos/sin table
#pragma unroll
    for (int rr = 0; rr < 4; ++rr)
#pragma unroll
        for (int q = 0; q < 10; ++q)
            sA[(rg + 64*rr)*40 + 10*cg + q] = acc[rr][q];
    {
        float ang = TWO_PI * (float)t * (1.0f/256.0f);
        float s, c; sincosf(ang, &s, &c);
        csp[t] = make_float2(c, s);
    }
    __syncthreads();

    // phase 2: X_low[kx,ky] = sum_h A[h][.] * e^{-2pi i kx h/256}
    if (t < 200) {
        const int p  = t >> 1;         // 0..99
        const int sh = t & 1;          // h-half; partner = adjacent lane
        const int kxg = p / 10, kyg = p % 10;
        const int kx0 = 2 * kxg;
        float a2[8];
#pragma unroll
        for (int q = 0; q < 8; q++) a2[q] = 0.f;
        for (int it = 0; it < 128; ++it) {
            int h = 128 * sh + it;
            float4 a = *(const float4*)(sA + h*40 + 4*kyg); // re0,im0,re1,im1
            int i0 = (kx0 * h) & 255;
            int i1 = (i0 + h) & 255;
            float2 cs0 = csp[i0];
            float2 cs1 = csp[i1];
            a2[0] += a.x*cs0.x + a.y*cs0.y;  a2[1] += a.y*cs0.x - a.x*cs0.y;
            a2[2] += a.z*cs0.x + a.w*cs0.y;  a2[3] += a.w*cs0.x - a.z*cs0.y;
            a2[4] += a.x*cs1.x + a.y*cs1.y;  a2[5] += a.y*cs1.x - a.x*cs1.y;
            a2[6] += a.z*cs1.x + a.w*cs1.y;  a2[7] += a.w*cs1.x - a.z*cs1.y;
        }
#pragma unroll
        for (int q = 0; q < 8; q++) a2[q] += __shfl_xor(a2[q], 1);
        if (sh == 0) {
            float* xl = ws + OFF_XL + (long)r * (NMODES * 2);
            *(float4*)(xl + 2*(kx0*20 + 2*kyg))       = make_float4(a2[0],a2[1],a2[2],a2[3]);
            *(float4*)(xl + 2*((kx0+1)*20 + 2*kyg))   = make_float4(a2[4],a2[5],a2[6],a2[7]);
        }
    }
}

// ---------------- channel mix: OL[b,o,m] = sum_i X[b,i,m]*W[i,o,m] --------------
__launch_bounds__(256, 4)
__global__ void mix_kernel(const float* __restrict__ wre, const float* __restrict__ wim,
                           float* __restrict__ ws) {
    __shared__ float sw[200];
    __shared__ float sx[800];
    const int t = threadIdx.x;
    const int blk = blockIdx.x;
    const int o  = blk >> 4;
    const int mq = (blk >> 2) & 3;
    const int bq = blk & 3;
    const int m0 = mq * 100;
    const float* XL = ws + OFF_XL;
    float acc[2][2];
    acc[0][0] = acc[0][1] = acc[1][0] = acc[1][1] = 0.f;
    for (int i = 0; i < NCI; ++i) {
        __syncthreads();
        if (t < 100)      sw[t] = wre[(long)(i * NCO + o) * NMODES + m0 + t];
        else if (t < 200) sw[t] = wim[(long)(i * NCO + o) * NMODES + m0 + (t - 100)];
#pragma unroll
        for (int j = 0; j < 4; ++j) {
            int u = t + 256 * j;
            if (u < 800) {
                int bl = u / 200, q = u % 200;
                int b = 4 * bq + bl;
                sx[u] = XL[((long)(b * NCI + i) * NMODES + m0) * 2 + q];
            }
        }
        __syncthreads();
#pragma unroll
        for (int j = 0; j < 2; ++j) {
            int v = t + 256 * j;
            if (v < 400) {
                int bl = v / 100, ml = v % 100;
                float xr = sx[bl*200 + 2*ml], xi = sx[bl*200 + 2*ml + 1];
                float wr = sw[ml], wi = sw[100 + ml];
                acc[j][0] += xr * wr - xi * wi;
                acc[j][1] += xr * wi + xi * wr;
            }
        }
    }
    float* OL = ws + OFF_OL;
#pragma unroll
    for (int j = 0; j < 2; ++j) {
        int v = t + 256 * j;
        if (v < 400) {
            int bl = v / 100, ml = v % 100;
            int b = 4 * bq + bl;
            long a = ((long)(b * NCO + o) * NMODES + m0 + ml) * 2;
            OL[a]     = acc[j][0];
            OL[a + 1] = acc[j][1];
        }
    }
}

// ---------------- inverse: OL -> out (fused H-iDFT then symmetric W-iDFT) -------
// grid 4096: (bo, hq); 256 threads; 3 blocks/CU
__launch_bounds__(256, 3)
__global__ void inv_kernel(const float* __restrict__ ws, float* __restrict__ out) {
    __shared__ float sm2[11712];
    float* sOL = sm2;            // 800
    float* cs  = sm2 + 800;      // 512
    float* sYr = sm2 + 1312;     // [20][68]
    float* sYi = sm2 + 2672;     // [20][68]
    float* sTc = sm2 + 4032;     // [20][16][12]
    float* sTs = sm2 + 7872;     // [20][16][12]
    const int t = threadIdx.x;
    const int blk = blockIdx.x;
    const int bo = blk >> 2;     // b*64+o
    const int hq = blk & 3;

    { float ang = TWO_PI * (float)t * (1.0f/256.0f); float s,c; sincosf(ang,&s,&c);
      cs[2*t] = c; cs[2*t+1] = s; }
    {
        const float* OL = ws + OFF_OL + (long)bo * (NMODES * 2);
#pragma unroll
        for (int j = 0; j < 4; ++j) {
            int u = t + 256 * j;
            if (u < 800) sOL[u] = OL[u];
        }
        const float* TI = ws + OFF_TINV;
#pragma unroll
        for (int j = 0; j < 8; ++j) {
            int u = t + 256 * j;
            if (u < 1920) *(float4*)(sTc + 4*u) = *(const float4*)(TI + 4*u);
        }
    }
    __syncthreads();

    // phase 1: Yc[ky][h] = sum_kx OL[kx][ky] e^{+2pi i kx h/256}
    {
        int hloc = t >> 2, kyq = t & 3;
        int h = hq * 64 + hloc;
        float a[5][2];
#pragma unroll
        for (int kk = 0; kk < 5; kk++) { a[kk][0] = 0.f; a[kk][1] = 0.f; }
        for (int kx = 0; kx < NM1; ++kx) {
            int idx = (kx * h) & 255;
            float c = cs[2*idx], s = cs[2*idx+1];
#pragma unroll
            for (int kk = 0; kk < 5; ++kk) {
                int ky = kyq * 5 + kk;
                float pr = sOL[2*(kx*NM2 + ky)], pi = sOL[2*(kx*NM2 + ky) + 1];
                a[kk][0] += pr * c - pi * s;
                a[kk][1] += pr * s + pi * c;
            }
        }
#pragma unroll
        for (int kk = 0; kk < 5; ++kk) {
            int ky = kyq * 5 + kk;
            sYr[ky*68 + hloc] = a[kk][0];
            sYi[ky*68 + hloc] = a[kk][1];
        }
    }
    __syncthreads();

    // phase 2: U = sum_ky Yr*Tc, V = sum_ky Yi*Ts; out[w]=U-V, out[256-w]=U+V
    {
        const int lg = t & 15;
        const int hg = t >> 4;
        float U[4][8], V[4][8];
#pragma unroll
        for (int rr = 0; rr < 4; rr++)
#pragma unroll
            for (int c = 0; c < 8; c++) { U[rr][c] = 0.f; V[rr][c] = 0.f; }
        for (int ky = 0; ky < 20; ++ky) {
            float4 yr = *(const float4*)(sYr + ky*68 + 4*hg);
            float4 yi = *(const float4*)(sYi + ky*68 + 4*hg);
            const float* tcp = sTc + ky*192 + lg*12;
            const float* tsp = sTs + ky*192 + lg*12;
            float4 c0 = *(const float4*)(tcp), c1 = *(const float4*)(tcp + 4);
            float4 s0 = *(const float4*)(tsp), s1 = *(const float4*)(tsp + 4);
            float ya[4] = {yr.x, yr.y, yr.z, yr.w};
            float yb[4] = {yi.x, yi.y, yi.z, yi.w};
            float tc[8] = {c0.x,c0.y,c0.z,c0.w, c1.x,c1.y,c1.z,c1.w};
            float ts[8] = {s0.x,s0.y,s0.z,s0.w, s1.x,s1.y,s1.z,s1.w};
#pragma unroll
            for (int rr = 0; rr < 4; ++rr)
#pragma unroll
                for (int c = 0; c < 8; ++c) {
                    U[rr][c] += ya[rr] * tc[c];
                    V[rr][c] += yb[rr] * ts[c];
                }
        }
        float* orow0 = out + (long)bo * (NH*NW) + (long)(hq*64 + 4*hg) * NW;
#pragma unroll
        for (int rr = 0; rr < 4; ++rr) {
            float* orow = orow0 + (long)rr * NW;
            float L[8], F[8];
#pragma unroll
            for (int c = 0; c < 8; ++c) { L[c] = U[rr][c] - V[rr][c]; F[c] = U[rr][c] + V[rr][c]; }
            int wl = 8*lg + 1;
            orow[wl] = L[0];
            *(float2*)(orow + wl + 1) = make_float2(L[1], L[2]);
            *(float4*)(orow + wl + 3) = make_float4(L[3], L[4], L[5], L[6]);
            orow[wl + 7] = L[7];
            *(float4*)(orow + 252 - 8*lg) = make_float4(F[3], F[2], F[1], F[0]);
            *(float4*)(orow + 248 - 8*lg) = make_float4(F[7], F[6], F[5], F[4]);
        }
    }
    if (t < 64) {
        float sum = 0.f;
        for (int ky = 0; ky < 20; ++ky)
            sum += sYr[ky*68 + t] * ((ky == 0) ? 1.0f : 2.0f);
        out[(long)bo * (NH*NW) + (long)(hq*64 + t) * NW] = sum * INV_N2;
    }
}

extern "C" void kernel_launch(void* const* d_in, const int* in_sizes, int n_in,
                              void* d_out, int out_size, void* d_ws, size_t ws_size,
                              hipStream_t stream) {
    const float* x   = (const float*)d_in[0];
    const float* wre = (const float*)d_in[1];
    const float* wim = (const float*)d_in[2];
    float* out = (float*)d_out;
    float* ws  = (float*)d_ws;

    init_tabs<<<dim3(78), dim3(256), 0, stream>>>(ws);
    fwd_kernel<<<dim3(NB * NCI), dim3(256), 0, stream>>>(x, ws);
    mix_kernel<<<dim3(1024), dim3(256), 0, stream>>>(wre, wim, ws);
    inv_kernel<<<dim3(NB * NCO * 4), dim3(256), 0, stream>>>(ws, out);
}

// Round 7
// 288.997 us; speedup vs baseline: 1.2123x; 1.0596x over previous
//
#include <hip/hip_runtime.h>

constexpr int NB = 16;
constexpr int NCI = 64;
constexpr int NCO = 64;
constexpr int NH = 256;
constexpr int NW = 256;
constexpr int NM1 = 20;
constexpr int NM2 = 20;
constexpr int NMODES = 400;

// workspace layout (float offsets)
constexpr long OFF_TWS  = 0;                                  // fwd twiddle [256][48]
constexpr long OFF_TINV = 12288;                              // Tc[20][16][12] | Ts[20][16][12]
constexpr long OFF_XL   = OFF_TINV + 7680;                    // [NB][NCI][400][2]
constexpr long OFF_OL   = OFF_XL + (long)NB*NCI*NMODES*2;     // [NB][NCO][400][2]

constexpr float TWO_PI = 6.28318530717958647692f;
constexpr float INV_N2 = 1.0f / 65536.0f;

// async global->LDS, 16 B per lane; LDS dest = wave-uniform base + lane*16
__device__ __forceinline__ void gload16(const float* g, float* l) {
    __builtin_amdgcn_global_load_lds(
        (const __attribute__((address_space(1))) unsigned int*)(g),
        (__attribute__((address_space(3))) unsigned int*)(l), 16, 0, 0);
}

// ---------------- table init ----------------------------------------------------
__global__ void init_tabs(float* __restrict__ ws) {
    int e = blockIdx.x * 256 + threadIdx.x;
    if (e < 12288) {
        int w = e / 48, s = e % 48;
        int cg = s / 12, q = s % 12;
        float v = 0.f;
        if (q < 10) {
            int n = 10 * cg + q, ky = n >> 1, p = n & 1;
            float ang = TWO_PI * (float)((ky * w) & 255) * (1.0f / 256.0f);
            float sn, cn; sincosf(ang, &sn, &cn);
            v = p ? -sn : cn;
        }
        ws[OFF_TWS + e] = v;
    } else if (e < 19968) {
        int f = e - 12288;
        int tb = f / 3840, rr = f % 3840;
        int ky = rr / 192, g = (rr % 192) / 12, q = rr % 12;
        float v = 0.f;
        if (q < 8) {
            int w = 8 * g + 1 + q;
            float ang = TWO_PI * (float)((ky * w) & 255) * (1.0f / 256.0f);
            float sn, cn; sincosf(ang, &sn, &cn);
            float cky = (ky == 0) ? 1.0f : 2.0f;
            v = (tb == 0 ? cn : sn) * cky * INV_N2;
        }
        ws[OFF_TINV + f] = v;
    }
}

// ---------------- forward: x -> X_low (fused W-DFT then H-DFT) ------------------
// one block per (b*64+i); 256 threads; 2 blocks/CU, pipelined staging
__launch_bounds__(256, 2)
__global__ void fwd_kernel(const float* __restrict__ x, float* __restrict__ ws) {
    __shared__ float sm[19456];        // dbuf: [2] x { sX[256][32], sT[32][48] }
    float* sA = sm;                    // [256][40] A[h][n] (10240), phase 2
    float2* csp = (float2*)(sm + 10240); // [256] cos/sin,           phase 2
    const int t = threadIdx.x;
    const int r = blockIdx.x;                 // b*64+i
    const float* xr = x + (long)r * (NH * NW);
    const float* tws = ws + OFF_TWS;

    const int rg = t >> 2;    // [0,64): h = rg + 64*rr
    const int cg = t & 3;     // [0,4):  n = 10*cg + q
    const int sw = rg & 7;    // x column swizzle key (h&7 == rg&7 for all rr)

    const int wid  = t >> 6, lane = t & 63;
    const int lrow = lane >> 3;                 // row within wave's 8-row stripe
    const int lcsw = 4 * ((lane & 7) ^ lrow);   // pre-swizzled source col (floats)

    float acc[4][10];
#pragma unroll
    for (int a0 = 0; a0 < 4; a0++)
#pragma unroll
        for (int a1 = 0; a1 < 10; a1++) acc[a0][a1] = 0.f;

#define STAGE(KC, SX, ST)                                                        \
    {                                                                            \
        const float* xc_ = xr + (KC) * 32;                                       \
        _Pragma("unroll")                                                        \
        for (int j = 0; j < 8; ++j) {                                            \
            const int rowbase = j * 32 + wid * 8;                                \
            gload16(xc_ + (long)(rowbase + lrow) * NW + lcsw, (SX) + rowbase*32);\
        }                                                                        \
        const float* tcc_ = tws + (long)(KC) * 1536;                             \
        gload16(tcc_ + wid * 256 + 4 * lane, (ST) + wid * 256);                  \
        if (wid < 2)                                                             \
            gload16(tcc_ + (wid + 4) * 256 + 4 * lane, (ST) + (wid + 4) * 256);  \
    }

    STAGE(0, sm, sm + 8192);
    __syncthreads();   // buf0 staged & visible

    for (int kc = 0; kc < 8; ++kc) {
        float* sX = sm + (kc & 1) * 9728;
        float* sT = sX + 8192;
        if (kc < 7) {
            float* nX = sm + ((kc + 1) & 1) * 9728;
            STAGE(kc + 1, nX, nX + 8192);     // issue async prefetch
        }
        // compute chunk kc: 8 w-quads (overlaps with in-flight prefetch)
#pragma unroll 2
        for (int wq = 0; wq < 8; ++wq) {
            float4 xq[4];
            const int xcol = 4 * (wq ^ sw);
#pragma unroll
            for (int rr = 0; rr < 4; ++rr)
                xq[rr] = *(const float4*)(sX + (rg + 64*rr)*32 + xcol);
#pragma unroll
            for (int ww = 0; ww < 4; ++ww) {
                const float* tp = sT + (4*wq + ww)*48 + 12*cg;
                float4 t0 = *(const float4*)(tp);
                float4 t1 = *(const float4*)(tp + 4);
                float4 t2 = *(const float4*)(tp + 8);
                float tv[10] = {t0.x,t0.y,t0.z,t0.w, t1.x,t1.y,t1.z,t1.w, t2.x,t2.y};
                float xa[4] = {xq[0][ww], xq[1][ww], xq[2][ww], xq[3][ww]};
#pragma unroll
                for (int rr = 0; rr < 4; ++rr)
#pragma unroll
                    for (int q = 0; q < 10; ++q)
                        acc[rr][q] += xa[rr] * tv[q];
            }
        }
        __syncthreads();   // drains vmcnt: prefetch done; all waves done reading sX
    }
#undef STAGE

    // write A[h][n] to LDS; regenerate cos/sin table
#pragma unroll
    for (int rr = 0; rr < 4; ++rr)
#pragma unroll
        for (int q = 0; q < 10; ++q)
            sA[(rg + 64*rr)*40 + 10*cg + q] = acc[rr][q];
    {
        float ang = TWO_PI * (float)t * (1.0f/256.0f);
        float s, c; sincosf(ang, &s, &c);
        csp[t] = make_float2(c, s);
    }
    __syncthreads();

    // phase 2: X_low[kx,ky] = sum_h A[h][.] * e^{-2pi i kx h/256}
    if (t < 200) {
        const int p  = t >> 1;         // 0..99
        const int sh = t & 1;          // h-half; partner = adjacent lane
        const int kxg = p / 10, kyg = p % 10;
        const int kx0 = 2 * kxg;
        float a2[8];
#pragma unroll
        for (int q = 0; q < 8; q++) a2[q] = 0.f;
        for (int it = 0; it < 128; ++it) {
            int h = 128 * sh + it;
            float4 a = *(const float4*)(sA + h*40 + 4*kyg); // re0,im0,re1,im1
            int i0 = (kx0 * h) & 255;
            int i1 = (i0 + h) & 255;
            float2 cs0 = csp[i0];
            float2 cs1 = csp[i1];
            a2[0] += a.x*cs0.x + a.y*cs0.y;  a2[1] += a.y*cs0.x - a.x*cs0.y;
            a2[2] += a.z*cs0.x + a.w*cs0.y;  a2[3] += a.w*cs0.x - a.z*cs0.y;
            a2[4] += a.x*cs1.x + a.y*cs1.y;  a2[5] += a.y*cs1.x - a.x*cs1.y;
            a2[6] += a.z*cs1.x + a.w*cs1.y;  a2[7] += a.w*cs1.x - a.z*cs1.y;
        }
#pragma unroll
        for (int q = 0; q < 8; q++) a2[q] += __shfl_xor(a2[q], 1);
        if (sh == 0) {
            float* xl = ws + OFF_XL + (long)r * (NMODES * 2);
            *(float4*)(xl + 2*(kx0*20 + 2*kyg))       = make_float4(a2[0],a2[1],a2[2],a2[3]);
            *(float4*)(xl + 2*((kx0+1)*20 + 2*kyg))   = make_float4(a2[4],a2[5],a2[6],a2[7]);
        }
    }
}

// ---------------- channel mix: OL[b,o,m] = sum_i X[b,i,m]*W[i,o,m] --------------
// grid 1024: (o, mq, bq); 256 threads; i staged in groups of 8
__launch_bounds__(256, 4)
__global__ void mix_kernel(const float* __restrict__ wre, const float* __restrict__ wim,
                           float* __restrict__ ws) {
    __shared__ float sw[1600];   // [8 i][re100|im100]
    __shared__ float sx[6400];   // [8 i][4 b][100 m][2]
    const int t = threadIdx.x;
    const int blk = blockIdx.x;
    const int o  = blk >> 4;
    const int mq = (blk >> 2) & 3;
    const int bq = blk & 3;
    const int m0 = mq * 100;
    const float* XL = ws + OFF_XL;
    float acc[2][2];
    acc[0][0] = acc[0][1] = acc[1][0] = acc[1][1] = 0.f;
    for (int ig = 0; ig < 8; ++ig) {
        const int i0 = ig * 8;
        __syncthreads();
#pragma unroll
        for (int j = 0; j < 7; ++j) {
            int u = t + 256 * j;
            if (u < 1600) {
                int il = u / 200, q = u % 200;
                long base = (long)((i0 + il) * NCO + o) * NMODES + m0;
                sw[u] = (q < 100) ? wre[base + q] : wim[base + (q - 100)];
            }
        }
#pragma unroll
        for (int j = 0; j < 25; ++j) {
            int u = t + 256 * j;
            if (u < 6400) {
                int il = u / 800, rest = u % 800;
                int bl = rest / 200, q = rest % 200;
                int b = 4 * bq + bl;
                sx[u] = XL[((long)(b * NCI + i0 + il) * NMODES + m0) * 2 + q];
            }
        }
        __syncthreads();
#pragma unroll
        for (int j = 0; j < 2; ++j) {
            int v = t + 256 * j;
            if (v < 400) {
                int bl = v / 100, ml = v % 100;
#pragma unroll
                for (int il = 0; il < 8; ++il) {
                    float xr = sx[il*800 + bl*200 + 2*ml];
                    float xi = sx[il*800 + bl*200 + 2*ml + 1];
                    float wr = sw[il*200 + ml], wi = sw[il*200 + 100 + ml];
                    acc[j][0] += xr * wr - xi * wi;
                    acc[j][1] += xr * wi + xi * wr;
                }
            }
        }
    }
    float* OL = ws + OFF_OL;
#pragma unroll
    for (int j = 0; j < 2; ++j) {
        int v = t + 256 * j;
        if (v < 400) {
            int bl = v / 100, ml = v % 100;
            int b = 4 * bq + bl;
            long a = ((long)(b * NCO + o) * NMODES + m0 + ml) * 2;
            OL[a]     = acc[j][0];
            OL[a + 1] = acc[j][1];
        }
    }
}

// ---------------- inverse: OL -> out (fused H-iDFT then symmetric W-iDFT) -------
// grid 4096: (bo, hq); 256 threads; 3 blocks/CU
__launch_bounds__(256, 3)
__global__ void inv_kernel(const float* __restrict__ ws, float* __restrict__ out) {
    __shared__ float sm2[11712];
    float* sOL = sm2;            // 800
    float* cs  = sm2 + 800;      // 512
    float* sYr = sm2 + 1312;     // [20][68]
    float* sYi = sm2 + 2672;     // [20][68]
    float* sTc = sm2 + 4032;     // [20][16][12]
    float* sTs = sm2 + 7872;     // [20][16][12]
    const int t = threadIdx.x;
    const int blk = blockIdx.x;
    const int bo = blk >> 2;     // b*64+o
    const int hq = blk & 3;

    { float ang = TWO_PI * (float)t * (1.0f/256.0f); float s,c; sincosf(ang,&s,&c);
      cs[2*t] = c; cs[2*t+1] = s; }
    {
        const float* OL = ws + OFF_OL + (long)bo * (NMODES * 2);
#pragma unroll
        for (int j = 0; j < 4; ++j) {
            int u = t + 256 * j;
            if (u < 800) sOL[u] = OL[u];
        }
        const float* TI = ws + OFF_TINV;
#pragma unroll
        for (int j = 0; j < 8; ++j) {
            int u = t + 256 * j;
            if (u < 1920) *(float4*)(sTc + 4*u) = *(const float4*)(TI + 4*u);
        }
    }
    __syncthreads();

    // phase 1: Yc[ky][h] = sum_kx OL[kx][ky] e^{+2pi i kx h/256}
    {
        int hloc = t >> 2, kyq = t & 3;
        int h = hq * 64 + hloc;
        float a[5][2];
#pragma unroll
        for (int kk = 0; kk < 5; kk++) { a[kk][0] = 0.f; a[kk][1] = 0.f; }
        for (int kx = 0; kx < NM1; ++kx) {
            int idx = (kx * h) & 255;
            float c = cs[2*idx], s = cs[2*idx+1];
#pragma unroll
            for (int kk = 0; kk < 5; ++kk) {
                int ky = kyq * 5 + kk;
                float pr = sOL[2*(kx*NM2 + ky)], pi = sOL[2*(kx*NM2 + ky) + 1];
                a[kk][0] += pr * c - pi * s;
                a[kk][1] += pr * s + pi * c;
            }
        }
#pragma unroll
        for (int kk = 0; kk < 5; ++kk) {
            int ky = kyq * 5 + kk;
            sYr[ky*68 + hloc] = a[kk][0];
            sYi[ky*68 + hloc] = a[kk][1];
        }
    }
    __syncthreads();

    // phase 2: U = sum_ky Yr*Tc, V = sum_ky Yi*Ts; out[w]=U-V, out[256-w]=U+V
    {
        const int lg = t & 15;
        const int hg = t >> 4;
        float U[4][8], V[4][8];
#pragma unroll
        for (int rr = 0; rr < 4; rr++)
#pragma unroll
            for (int c = 0; c < 8; c++) { U[rr][c] = 0.f; V[rr][c] = 0.f; }
        for (int ky = 0; ky < 20; ++ky) {
            float4 yr = *(const float4*)(sYr + ky*68 + 4*hg);
            float4 yi = *(const float4*)(sYi + ky*68 + 4*hg);
            const float* tcp = sTc + ky*192 + lg*12;
            const float* tsp = sTs + ky*192 + lg*12;
            float4 c0 = *(const float4*)(tcp), c1 = *(const float4*)(tcp + 4);
            float4 s0 = *(const float4*)(tsp), s1 = *(const float4*)(tsp + 4);
            float ya[4] = {yr.x, yr.y, yr.z, yr.w};
            float yb[4] = {yi.x, yi.y, yi.z, yi.w};
            float tc[8] = {c0.x,c0.y,c0.z,c0.w, c1.x,c1.y,c1.z,c1.w};
            float ts[8] = {s0.x,s0.y,s0.z,s0.w, s1.x,s1.y,s1.z,s1.w};
#pragma unroll
            for (int rr = 0; rr < 4; ++rr)
#pragma unroll
                for (int c = 0; c < 8; ++c) {
                    U[rr][c] += ya[rr] * tc[c];
                    V[rr][c] += yb[rr] * ts[c];
                }
        }
        float* orow0 = out + (long)bo * (NH*NW) + (long)(hq*64 + 4*hg) * NW;
#pragma unroll
        for (int rr = 0; rr < 4; ++rr) {
            float* orow = orow0 + (long)rr * NW;
            float L[8], F[8];
#pragma unroll
            for (int c = 0; c < 8; ++c) { L[c] = U[rr][c] - V[rr][c]; F[c] = U[rr][c] + V[rr][c]; }
            int wl = 8*lg + 1;
            orow[wl] = L[0];
            *(float2*)(orow + wl + 1) = make_float2(L[1], L[2]);
            *(float4*)(orow + wl + 3) = make_float4(L[3], L[4], L[5], L[6]);
            orow[wl + 7] = L[7];
            *(float4*)(orow + 252 - 8*lg) = make_float4(F[3], F[2], F[1], F[0]);
            *(float4*)(orow + 248 - 8*lg) = make_float4(F[7], F[6], F[5], F[4]);
        }
    }
    if (t < 64) {
        float sum = 0.f;
        for (int ky = 0; ky < 20; ++ky)
            sum += sYr[ky*68 + t] * ((ky == 0) ? 1.0f : 2.0f);
        out[(long)bo * (NH*NW) + (long)(hq*64 + t) * NW] = sum * INV_N2;
    }
}

extern "C" void kernel_launch(void* const* d_in, const int* in_sizes, int n_in,
                              void* d_out, int out_size, void* d_ws, size_t ws_size,
                              hipStream_t stream) {
    const float* x   = (const float*)d_in[0];
    const float* wre = (const float*)d_in[1];
    const float* wim = (const float*)d_in[2];
    float* out = (float*)d_out;
    float* ws  = (float*)d_ws;

    init_tabs<<<dim3(78), dim3(256), 0, stream>>>(ws);
    fwd_kernel<<<dim3(NB * NCI), dim3(256), 0, stream>>>(x, ws);
    mix_kernel<<<dim3(1024), dim3(256), 0, stream>>>(wre, wim, ws);
    inv_kernel<<<dim3(NB * NCO * 4), dim3(256), 0, stream>>>(ws, out);
}